// Round 2
// baseline (500.165 us; speedup 1.0000x reference)
//
#include <hip/hip_runtime.h>
#include <hip/hip_bf16.h>
#include <math.h>

// Squeeze-Excitation, x: (64, 256, 64, 64) fp32
//   pooled = mean(x, spatial)                      [64, 256]
//   h      = gelu_exact(pooled @ w1^T)             [64, 16]
//   scale  = sigmoid(h @ w2^T)                     [64, 256]
//   out    = x * scale[:, :, None, None]
//
// B=64, C=256, HW=4096, bottleneck=16.
// Memory-bound: 256 MiB read (pool) + 256 MiB read + 256 MiB write (scale).
// Roofline @6.3 TB/s achievable: ~122 us.
//
// Workspace use: 2 * 16384 * 4 B = 128 KiB of d_ws.

#define B_DIM 64
#define C_DIM 256
#define HW_DIM 4096           // 64*64
#define BOT 16
#define N4_TOTAL (64ull * 256ull * 1024ull)   // total float4 count = 16,777,216

// ---------------- Kernel 1: global average pool ----------------
// One block of 256 threads per (b,c) plane. Plane = 4096 contiguous floats
// = 1024 float4 -> 4 float4 per thread, fully coalesced.
__global__ __launch_bounds__(256) void se_pool_kernel(
    const float* __restrict__ x, float* __restrict__ pooled) {
    const int bc = blockIdx.x;  // 0 .. 16383
    const float4* xp = reinterpret_cast<const float4*>(x) + (size_t)bc * 1024;
    const int t = threadIdx.x;

    float sum = 0.0f;
#pragma unroll
    for (int i = 0; i < 4; ++i) {
        float4 v = xp[t + 256 * i];
        sum += (v.x + v.y) + (v.z + v.w);
    }
    // wave-64 shuffle reduction
#pragma unroll
    for (int off = 32; off > 0; off >>= 1)
        sum += __shfl_down(sum, off, 64);

    __shared__ float wsum[4];
    const int wave = t >> 6;
    const int lane = t & 63;
    if (lane == 0) wsum[wave] = sum;
    __syncthreads();
    if (t == 0) {
        float s = (wsum[0] + wsum[1]) + (wsum[2] + wsum[3]);
        pooled[bc] = s * (1.0f / 4096.0f);
    }
}

// ---------------- Kernel 2: tiny FC stack ----------------
// One block per batch. pooled row (256 f32) in LDS; 16 threads do the
// 256-wide dot for h (GELU exact via erff); then every thread c computes
// the 16-wide dot for its channel's sigmoid scale.
__global__ __launch_bounds__(256) void se_fc_kernel(
    const float* __restrict__ pooled,
    const float* __restrict__ w1,   // (16, 256) row-major
    const float* __restrict__ w2,   // (256, 16) row-major
    float* __restrict__ scale) {
    const int b = blockIdx.x;  // 0 .. 63
    const int t = threadIdx.x;

    __shared__ float p_s[C_DIM];
    __shared__ float h_s[BOT];

    p_s[t] = pooled[b * C_DIM + t];
    __syncthreads();

    if (t < BOT) {
        const float* w1r = w1 + t * C_DIM;
        float acc = 0.0f;
#pragma unroll 8
        for (int c = 0; c < C_DIM; ++c) acc += p_s[c] * w1r[c];
        // exact GELU: 0.5*x*(1+erf(x/sqrt(2)))
        h_s[t] = 0.5f * acc * (1.0f + erff(acc * 0.70710678118654752440f));
    }
    __syncthreads();

    const float* w2r = w2 + t * BOT;
    float s = 0.0f;
#pragma unroll
    for (int j = 0; j < BOT; ++j) s += h_s[j] * w2r[j];
    scale[b * C_DIM + t] = 1.0f / (1.0f + expf(-s));
}

// ---------------- Kernel 3: channel-wise scale ----------------
// Grid-stride float4 multiply. Plane = 1024 float4s, so scale index = i >> 10.
__global__ __launch_bounds__(256) void se_scale_kernel(
    const float* __restrict__ x, const float* __restrict__ scale,
    float* __restrict__ out) {
    const float4* x4 = reinterpret_cast<const float4*>(x);
    float4* o4 = reinterpret_cast<float4*>(out);
    const size_t stride = (size_t)gridDim.x * blockDim.x;
    for (size_t i = (size_t)blockIdx.x * blockDim.x + threadIdx.x;
         i < N4_TOTAL; i += stride) {
        const float s = scale[i >> 10];
        float4 v = x4[i];
        v.x *= s; v.y *= s; v.z *= s; v.w *= s;
        o4[i] = v;
    }
}

extern "C" void kernel_launch(void* const* d_in, const int* in_sizes, int n_in,
                              void* d_out, int out_size, void* d_ws, size_t ws_size,
                              hipStream_t stream) {
    const float* x  = (const float*)d_in[0];
    const float* w1 = (const float*)d_in[1];
    const float* w2 = (const float*)d_in[2];
    float* out = (float*)d_out;

    // workspace layout: pooled [16384 f32] | scale [16384 f32]  (128 KiB)
    float* pooled = (float*)d_ws;
    float* scale  = pooled + B_DIM * C_DIM;

    se_pool_kernel<<<B_DIM * C_DIM, 256, 0, stream>>>(x, pooled);
    se_fc_kernel<<<B_DIM, 256, 0, stream>>>(pooled, w1, w2, scale);
    // 2048 blocks x 256 threads, grid-stride (32 float4 per thread)
    se_scale_kernel<<<2048, 256, 0, stream>>>(x, scale, out);
}